// Round 4
// baseline (79.959 us; speedup 1.0000x reference)
//
#include <hip/hip_runtime.h>
#include <cmath>
#include <cstdint>

// Problem: B=2, C=32, Z=4, E=2, N=4096. One candidate point per lattice cell,
// cell pitch (0.78125, 0.78125, 0.75); offsets in [0,1) cell units.
// => dist < ele_d (0.74 / 0.528) pairs confined to 3x3x3 cells.
// => any point outside the xy +-2 cell window is >= 2*0.78125 = 1.5625*(1-eps)
//    away: a windowed argmin < GUARD=1.4999 is provably the global argmin.
namespace {
constexpr int NPT  = 4096;

// output offsets (floats), reference return order
constexpr int O_PPOS  = 0;
constexpr int O_MASKP = 49152;
constexpr int O_KEEP  = 65536;
constexpr int O_TPOS  = 81920;
constexpr int O_MASKT = 131072;
constexpr int O_TPT   = 147456;
constexpr int O_TPP   = 163840;
constexpr int O_TPTN  = 180224;
constexpr int O_TPPN  = 196608;

constexpr float GUARD = 1.4999f;
} // namespace

__device__ __forceinline__ unsigned long long shfl_xor_u64(unsigned long long v, int m) {
    unsigned lo = (unsigned)v, hi = (unsigned)(v >> 32);
    lo = __shfl_xor(lo, m); hi = __shfl_xor(hi, m);
    return ((unsigned long long)hi << 32) | lo;
}

// position from raw input + cell index — bit-identical everywhere (contract off,
// lattice constants 25/32 and 3/4 exactly representable)
__device__ __forceinline__ float3 cellpos(float4 p, int n) {
#pragma clang fp contract(off)
    float fx = (float)(n >> 7), fy = (float)((n >> 2) & 31), fz = (float)(n & 3);
    float3 r;
    r.x = (p.x + fx) * 0.78125f;
    r.y = (p.y + fy) * 0.78125f;
    r.z = (p.z + fz) * 0.75f;
    return r;
}
__device__ __forceinline__ float dist2v(float4 a, float4 b) {
#pragma clang fp contract(off)
    float dx = a.x - b.x, dy = a.y - b.y, dz = a.z - b.z;
    float d2 = dx * dx + dy * dy;
    return d2 + dz * dz;   // numpy sum order: (x+y)+z
}
__device__ __forceinline__ float dist2f(float3 a, float3 b) {
#pragma clang fp contract(off)
    float dx = a.x - b.x, dy = a.y - b.y, dz = a.z - b.z;
    float d2 = dx * dx + dy * dy;
    return d2 + dz * dz;
}

// ---------------------------------------------------------------------------
// K1: fused NMS. Block = (slice s, gx plane pair). Stages the 6-plane pred
// window (pos + key, key = valid ? conf : -1) in LDS, computes restrain for the
// 4-plane halo into LDS, then suppression + keep for the inner 2 planes.
// prec(i,j) = (c_i > c_j) || (c_i == c_j && i < j)   [stable desc-sort order]
__global__ void __launch_bounds__(256) k_nms(const float4* __restrict__ pred,
                                             float* __restrict__ out,
                                             unsigned char* __restrict__ keepu,
                                             float s0, float s1) {
#pragma clang fp contract(off)
    __shared__ float4 pw[6][128];          // planes gx0-2 .. gx0+3: (x,y,z,key)
    __shared__ unsigned char rsh[4][128];  // restrain, planes gx0-1 .. gx0+2
    int bid = blockIdx.x;
    int s = bid >> 4, gx0 = (bid & 15) * 2;
    int b = s >> 1, e = s & 1;
    int base4 = b * 8192 + e;
    float se = (s & 1) ? s1 : s0;

    // stage 6 planes (OOB planes: key=-1 gates everything)
    for (int idx = (int)threadIdx.x; idx < 768; idx += 256) {
        int p = idx >> 7, r = idx & 127;
        int gx = gx0 - 2 + p;
        float4 v = make_float4(0.f, 0.f, 0.f, -1.0f);
        if ((unsigned)gx <= 31u) {
            int n = gx * 128 + r;
            float4 raw = pred[base4 + n * 2];
            float3 q = cellpos(raw, n);
            v = make_float4(q.x, q.y, q.z, raw.w > 0.5f ? raw.w : -1.0f);
        }
        pw[p][r] = v;
    }
    __syncthreads();

    // restrain for the 4-plane halo (512 rows, 2 per thread)
    for (int ii = 0; ii < 2; ++ii) {
        int idx = (int)threadIdx.x + ii * 256;
        int p2 = idx >> 7, r = idx & 127;
        int gx = gx0 - 1 + p2, gy = r >> 2;
        float4 pj = pw[p2 + 1][r];
        unsigned c = 0;
        if (pj.w > 0.0f && (unsigned)gx <= 31u) {
            int n = gx * 128 + r;
            for (int dx = -1; dx <= 1; ++dx) {
                for (int dy = -1; dy <= 1; ++dy) {
                    int ny = gy + dy;
                    if ((unsigned)ny > 31u) continue;
#pragma unroll
                    for (int nz = 0; nz < 4; ++nz) {
                        int rr = ny * 4 + nz;
                        float4 pi = pw[p2 + 1 + dx][rr];
                        int ni = (gx + dx) * 128 + rr;
                        float d2 = dist2v(pj, pi);
                        bool prec = (pi.w > pj.w) || ((pi.w == pj.w) && (ni < n));
                        if ((pi.w > 0.0f) && (d2 < se) && prec) c++;
                    }
                }
            }
        }
        rsh[p2][r] = (unsigned char)c;
    }
    __syncthreads();

    // suppression + outputs for the inner 2 planes (1 row/thread)
    int t = (int)threadIdx.x;
    int pg = t >> 7, r = t & 127;
    int gx = gx0 + pg, gy = r >> 2;
    int n = gx * 128 + r;
    int row = s * NPT + n;
    float4 pj = pw[pg + 2][r];
    out[O_PPOS + row * 3 + 0] = pj.x;
    out[O_PPOS + row * 3 + 1] = pj.y;
    out[O_PPOS + row * 3 + 2] = pj.z;
    bool valid = pj.w > 0.0f;
    out[O_MASKP + row] = valid ? 1.0f : 0.0f;
    bool sup = false;
    if (valid) {
        for (int dx = -1; dx <= 1; ++dx) {
            for (int dy = -1; dy <= 1; ++dy) {
                int ny = gy + dy;
                if ((unsigned)ny > 31u) continue;
#pragma unroll
                for (int nz = 0; nz < 4; ++nz) {
                    int rr = ny * 4 + nz;
                    float4 pi = pw[pg + 2 + dx][rr];
                    int ni = (gx + dx) * 128 + rr;
                    float d2 = dist2v(pj, pi);
                    bool prec = (pi.w > pj.w) || ((pi.w == pj.w) && (ni < n));
                    bool flg = (pi.w > 0.0f) && (rsh[pg + 1 + dx][rr] == 0);
                    sup = sup || (flg && (d2 < se) && prec);
                }
            }
        }
    }
    bool keep = valid && !sup;
    out[O_KEEP + row] = keep ? 1.0f : 0.0f;
    keepu[row] = keep ? 1 : 0;
}

// ---------------------------------------------------------------------------
// K2: fused match (4 threads/row). 5x5 xy window x full z, both variants,
// exact any-masks (27-cell superset), GUARD-verified argmin; rare inline
// full-row fallback by the owning quad.
__global__ void __launch_bounds__(256) k_match(const float4* __restrict__ pred,
                                               const float4* __restrict__ tgt,
                                               const unsigned char* __restrict__ keepu,
                                               float* __restrict__ out,
                                               float s0, float s1) {
#pragma clang fp contract(off)
    int tid = blockIdx.x * 256 + (int)threadIdx.x;
    int row = tid >> 2, h = tid & 3;
    int n = row & (NPT - 1), s = row >> 12, b = s >> 1, e = s & 1;
    int base4 = b * 8192 + e, srow = s * NPT;
    float se = (s & 1) ? s1 : s0;
    float4 t4 = tgt[base4 + n * 2];
    float3 tj = cellpos(t4, n);
    bool tv = t4.w > 0.5f;
    if (h == 0) {
        out[O_TPOS + row * 3 + 0] = tj.x;
        out[O_TPOS + row * 3 + 1] = tj.y;
        out[O_TPOS + row * 3 + 2] = tj.z;
        out[O_MASKT + row] = tv ? 1.0f : 0.0f;
    }
    if (!tv) {   // quad-uniform: all-inf row -> masks 0, idx 0
        if (h == 0) {
            out[O_TPT + row] = 0.0f; out[O_TPTN + row] = 0.0f;
            out[O_TPP + row] = 0.0f; out[O_TPPN + row] = 0.0f;
        }
        return;
    }
    int gx = n >> 7, gy = (n >> 2) & 31;
    unsigned long long bs = ~0ull, bn = ~0ull;
    unsigned as_ = 0, an_ = 0;
    for (int qq = 0; qq < 7; ++qq) {
        int q = qq * 4 + h;
        if (q > 24) continue;
        int nx = gx + q / 5 - 2, ny = gy + q % 5 - 2;
        if ((unsigned)nx > 31u || (unsigned)ny > 31u) continue;
        int nb = nx * 128 + ny * 4;
#pragma unroll
        for (int nz = 0; nz < 4; ++nz) {
            int ni = nb + nz;
            float4 pi = pred[base4 + ni * 2];
            float3 qi = cellpos(pi, ni);
            float d2 = dist2f(tj, qi);
            float dist = sqrtf(d2);
            unsigned long long enc =
                ((unsigned long long)__float_as_uint(dist) << 32) | (unsigned)ni;
            if (pi.w > 0.5f) { if (enc < bs) bs = enc; if (d2 < se) as_ = 1u; }
            if (keepu[srow + ni]) { if (enc < bn) bn = enc; if (d2 < se) an_ = 1u; }
        }
    }
    for (int m = 1; m < 4; m <<= 1) {
        unsigned long long o = shfl_xor_u64(bs, m); if (o < bs) bs = o;
        o = shfl_xor_u64(bn, m); if (o < bn) bn = o;
        as_ |= __shfl_xor(as_, m);
        an_ |= __shfl_xor(an_, m);
    }
    if (h == 0) {
        out[O_TPT + row]  = as_ ? 1.0f : 0.0f;
        out[O_TPTN + row] = an_ ? 1.0f : 0.0f;
    }
    // empty best -> hi word 0xFFFFFFFF = NaN -> compare false -> fallback
    bool acc_s = __uint_as_float((unsigned)(bs >> 32)) < GUARD;
    bool acc_n = __uint_as_float((unsigned)(bn >> 32)) < GUARD;
    if (acc_s && acc_n) {
        if (h == 0) {
            out[O_TPP + row]  = (float)(unsigned)(bs & 0xffffffffull);
            out[O_TPPN + row] = (float)(unsigned)(bn & 0xffffffffull);
        }
        return;
    }
    // inline exact full-row fallback (quad-uniform; independent iterations)
    bs = ~0ull; bn = ~0ull;
#pragma unroll 4
    for (int k = h; k < NPT; k += 4) {
        float4 pi = pred[base4 + k * 2];
        float3 qi = cellpos(pi, k);
        float d2 = dist2f(tj, qi);
        float dist = sqrtf(d2);
        unsigned long long enc =
            ((unsigned long long)__float_as_uint(dist) << 32) | (unsigned)k;
        if (pi.w > 0.5f && enc < bs) bs = enc;
        if (keepu[srow + k] && enc < bn) bn = enc;
    }
    for (int m = 1; m < 4; m <<= 1) {
        unsigned long long o = shfl_xor_u64(bs, m); if (o < bs) bs = o;
        o = shfl_xor_u64(bn, m); if (o < bn) bn = o;
    }
    if (h == 0) {
        unsigned is_ = (bs == ~0ull) ? 0u : (unsigned)(bs & 0xffffffffull);
        unsigned in_ = (bn == ~0ull) ? 0u : (unsigned)(bn & 0xffffffffull);
        out[O_TPP + row]  = (float)is_;
        out[O_TPPN + row] = (float)in_;
    }
}

// ---------------------------------------------------------------------------
// host: smallest f with sqrtf(f) >= t, so (d2 < f) <=> (sqrtf(d2) < t) bit-exactly.
static float sq_boundary(float t) {
    float f = (float)((double)t * (double)t);
    while (sqrtf(f) >= t) f = nextafterf(f, 0.0f);
    while (sqrtf(f) < t)  f = nextafterf(f, __builtin_inff());
    return f;
}

extern "C" void kernel_launch(void* const* d_in, const int* in_sizes, int n_in,
                              void* d_out, int out_size, void* d_ws, size_t ws_size,
                              hipStream_t stream) {
    (void)in_sizes; (void)n_in; (void)out_size; (void)ws_size;
    const float4* pred = (const float4*)d_in[0];
    const float4* tgt  = (const float4*)d_in[1];
    float* out = (float*)d_out;
    unsigned char* keepu = (unsigned char*)d_ws;

    float s0 = sq_boundary(0.74f);    // ELE_D[0]
    float s1 = sq_boundary(0.528f);   // ELE_D[1]

    k_nms  <<<dim3(64),  dim3(256), 0, stream>>>(pred, out, keepu, s0, s1);
    k_match<<<dim3(256), dim3(256), 0, stream>>>(pred, tgt, keepu, out, s0, s1);
}